// Round 3
// baseline (321.807 us; speedup 1.0000x reference)
//
#include <hip/hip_runtime.h>

#define BLOCK 1024          // 16 waves/block; 2 blocks/CU -> 32 waves/CU (max)
#define SPB   4             // segments per block

// Branch-free BCE matching jnp: -(t*clip(log p,-100) + (1-t)*clip(log1p(-p),-100))
__device__ __forceinline__ float bce_elem(float p, float t) {
    float lp  = fmaxf(__logf(p), -100.0f);
    float l1p = fmaxf(__logf(1.0f - p), -100.0f);
    return -__builtin_fmaf(t, lp - l1p, l1p);
}

// Wave-cooperative lower_bound: first i in [0,n) with a[i] >= v (a ascending).
__device__ __forceinline__ int wave_lower_bound(const int* __restrict__ a, int n, int v) {
    const int lane = threadIdx.x & 63;
    int lo = 0, hi = n;
    while (hi - lo > 64) {
        int range  = hi - lo;
        int stride = range / 65 + 1;
        int idx    = lo + (lane + 1) * stride;
        bool lt    = (idx < hi) && (a[idx] < v);
        int  c     = __popcll(__ballot(lt));
        int  nlo   = lo + c * stride;
        int  nhi   = nlo + stride;
        if (nhi > hi) nhi = hi;
        lo = nlo; hi = nhi;
    }
    int idx = lo + lane;
    bool ge = (idx >= hi) || (a[idx] >= v);
    unsigned long long bal = __ballot(ge);
    return bal ? (lo + __ffsll(bal) - 1) : hi;
}

// Route (val,mf) of element e into one of 4 named accumulator pairs by segment.
// Named scalars only (runtime-indexed arrays would spill to scratch).
#define ACC(e, val, mf)                                                        \
    do {                                                                       \
        int s_ = ((e) >= L1) + ((e) >= L2) + ((e) >= L3);                      \
        if      (s_ == 0) { b0 += (val); c0 += (mf); }                         \
        else if (s_ == 1) { b1 += (val); c1 += (mf); }                         \
        else if (s_ == 2) { b2 += (val); c2 += (mf); }                         \
        else              { b3 += (val); c3 += (mf); }                         \
    } while (0)

// One block per 4 consecutive segments (Bseg=2048 -> 512 blocks, 2/CU).
// 5 boundary searches run concurrently on waves 0..4. Hot loop: 3 coalesced
// float4 streams with predicated 4-way segment accumulation. Final total is
// computed by the last block to finish (atomic counter) -- no second launch.
__global__ __launch_bounds__(BLOCK, 8) void seg_kernel(
    const float* __restrict__ pred, const float* __restrict__ tgt,
    const int* __restrict__ batch, const int* __restrict__ mask,
    const float* __restrict__ sat_pred, const float* __restrict__ sat_tgt,
    float* __restrict__ per_graph, unsigned* __restrict__ counter,
    float* __restrict__ out, int n, int Bseg, int nblocks)
{
    const int g      = blockIdx.x;
    const int tid    = threadIdx.x;
    const int wid    = tid >> 6;
    const int segbase = g * SPB;

    __shared__ int sh_lo[SPB + 1];
    if (wid <= SPB) {                          // waves 0..4 search concurrently
        int target = segbase + wid;
        if (target > Bseg) target = Bseg;
        int r = wave_lower_bound(batch, n, target);
        if ((tid & 63) == 0) sh_lo[wid] = r;
    }
    __syncthreads();
    const int L0 = sh_lo[0], L1 = sh_lo[1], L2 = sh_lo[2],
              L3 = sh_lo[3], L4 = sh_lo[4];   // block owns [L0, L4)

    float b0 = 0, c0 = 0, b1 = 0, c1 = 0, b2 = 0, c2 = 0, b3 = 0, c3 = 0;

    int a0 = (L0 + 3) & ~3;                   // first 16B-aligned element
    if (a0 > L4) a0 = L4;
    const int nvec = (L4 - a0) >> 2;
    const int a1   = a0 + (nvec << 2);

    // scalar head (<=3 elems)
    for (int i = L0 + tid; i < a0; i += BLOCK) {
        float mf = (float)mask[i];
        float v  = bce_elem(pred[i] * mf, tgt[i]);
        ACC(i, v, mf);
    }

    // vector body: 3 coalesced float4 streams
    const float4* p4 = reinterpret_cast<const float4*>(pred) + (a0 >> 2);
    const float4* t4 = reinterpret_cast<const float4*>(tgt)  + (a0 >> 2);
    const int4*   m4 = reinterpret_cast<const int4*>(mask)   + (a0 >> 2);
    for (int v = tid; v < nvec; v += BLOCK) {
        float4 p = p4[v];
        float4 t = t4[v];
        int4   m = m4[v];
        const int e0 = a0 + (v << 2);
        float m0 = (float)m.x, m1 = (float)m.y, m2 = (float)m.z, m3 = (float)m.w;
        float v0 = bce_elem(p.x * m0, t.x);
        float v1 = bce_elem(p.y * m1, t.y);
        float v2 = bce_elem(p.z * m2, t.z);
        float v3 = bce_elem(p.w * m3, t.w);
        int slo = (e0 >= L1) + (e0 >= L2) + (e0 >= L3);
        int shi = ((e0 + 3) >= L1) + ((e0 + 3) >= L2) + ((e0 + 3) >= L3);
        if (slo == shi) {                      // whole group in one segment (common)
            float vs = (v0 + v1) + (v2 + v3);
            float ms = (m0 + m1) + (m2 + m3);
            if      (slo == 0) { b0 += vs; c0 += ms; }
            else if (slo == 1) { b1 += vs; c1 += ms; }
            else if (slo == 2) { b2 += vs; c2 += ms; }
            else               { b3 += vs; c3 += ms; }
        } else {                               // boundary-straddling group (rare)
            ACC(e0,     v0, m0);
            ACC(e0 + 1, v1, m1);
            ACC(e0 + 2, v2, m2);
            ACC(e0 + 3, v3, m3);
        }
    }

    // scalar tail (<=3 elems)
    for (int i = a1 + tid; i < L4; i += BLOCK) {
        float mf = (float)mask[i];
        float v  = bce_elem(pred[i] * mf, tgt[i]);
        ACC(i, v, mf);
    }

    // wave reduction of 4 accumulator pairs
    #pragma unroll
    for (int o = 32; o > 0; o >>= 1) {
        b0 += __shfl_xor(b0, o);  c0 += __shfl_xor(c0, o);
        b1 += __shfl_xor(b1, o);  c1 += __shfl_xor(c1, o);
        b2 += __shfl_xor(b2, o);  c2 += __shfl_xor(c2, o);
        b3 += __shfl_xor(b3, o);  c3 += __shfl_xor(c3, o);
    }
    __shared__ float red[16][8];
    if ((tid & 63) == 0) {
        float* r = red[wid];
        r[0] = b0; r[1] = c0; r[2] = b1; r[3] = c1;
        r[4] = b2; r[5] = c2; r[6] = b3; r[7] = c3;
    }
    __syncthreads();
    if (tid < SPB) {
        float sbce = 0.0f, scnt = 0.0f;
        #pragma unroll
        for (int w = 0; w < BLOCK / 64; ++w) {
            sbce += red[w][2 * tid];
            scnt += red[w][2 * tid + 1];
        }
        const int seg = segbase + tid;
        if (seg < Bseg) {
            float pg = (scnt > 0.0f) ? sbce / fmaxf(scnt, 1.0f) : 0.0f;
            pg += bce_elem(sat_pred[seg], sat_tgt[seg]) * ((1.0f / 50.0f) / (float)Bseg);
            per_graph[seg] = pg;
        }
    }

    // last-block-done final reduction (replaces the second launch)
    __syncthreads();                           // per_graph stores done block-wide
    __threadfence();                           // make them device-visible
    __shared__ unsigned s_old;
    if (tid == 0) s_old = atomicAdd(counter, 1u);
    __syncthreads();
    if (s_old == (unsigned)(nblocks - 1)) {
        __threadfence();
        float local = 0.0f;
        for (int i = tid; i < Bseg; i += BLOCK)
            local += __hip_atomic_load(&per_graph[i], __ATOMIC_RELAXED,
                                       __HIP_MEMORY_SCOPE_AGENT);
        #pragma unroll
        for (int o = 32; o > 0; o >>= 1) local += __shfl_xor(local, o);
        __shared__ float wsum[16];
        if ((tid & 63) == 0) wsum[wid] = local;
        __syncthreads();
        if (tid == 0) {
            float s = 0.0f;
            #pragma unroll
            for (int w = 0; w < BLOCK / 64; ++w) s += wsum[w];
            out[0] = s;
        }
    }
}

extern "C" void kernel_launch(void* const* d_in, const int* in_sizes, int n_in,
                              void* d_out, int out_size, void* d_ws, size_t ws_size,
                              hipStream_t stream) {
    const float* y_mus_pred = (const float*)d_in[0];
    const float* y_mus      = (const float*)d_in[1];
    const float* y_sat_pred = (const float*)d_in[2];
    const float* y_sat      = (const float*)d_in[3];
    const int*   batch      = (const int*)d_in[4];
    const int*   mask       = (const int*)d_in[5];

    const int n    = in_sizes[0];
    const int Bseg = in_sizes[2];

    unsigned* counter   = (unsigned*)d_ws;                   // 4 B, zeroed each launch
    float*    per_graph = (float*)((char*)d_ws + 256);       // Bseg floats

    const int nblocks = (Bseg + SPB - 1) / SPB;

    hipMemsetAsync(counter, 0, sizeof(unsigned), stream);    // capture-safe
    seg_kernel<<<nblocks, BLOCK, 0, stream>>>(
        y_mus_pred, y_mus, batch, mask, y_sat_pred, y_sat,
        per_graph, counter, (float*)d_out, n, Bseg, nblocks);
}

// Round 5
// 151.297 us; speedup vs baseline: 2.1270x; 2.1270x over previous
//
#include <hip/hip_runtime.h>

#define BLOCK 256

// Native clang vector types: __builtin_nontemporal_load requires pointers to
// scalar/vector-of-scalar, not HIP_vector_type structs (r4 compile failure).
typedef float fx4 __attribute__((ext_vector_type(4)));
typedef int   ix4 __attribute__((ext_vector_type(4)));

// Branch-free BCE matching jnp: -(t*clip(log p,-100) + (1-t)*clip(log1p(-p),-100))
// log1p(-p) -> __logf(1-p): abs err ~6e-8, far inside the threshold.
__device__ __forceinline__ float bce_elem(float p, float t) {
    float lp  = fmaxf(__logf(p), -100.0f);        // v_log_f32(0) = -inf -> clamped
    float l1p = fmaxf(__logf(1.0f - p), -100.0f);
    return -__builtin_fmaf(t, lp - l1p, l1p);     // -(t*(lp-l1p) + l1p)
}

// Wave-cooperative lower_bound: first i in [0,n) with a[i] >= v (a ascending).
// 65-ary search: 4 rounds of dependent gathers for n=8M.
__device__ __forceinline__ int wave_lower_bound(const int* __restrict__ a, int n, int v) {
    const int lane = threadIdx.x & 63;
    int lo = 0, hi = n;
    while (hi - lo > 64) {
        int range  = hi - lo;
        int stride = range / 65 + 1;
        int idx    = lo + (lane + 1) * stride;
        bool lt    = (idx < hi) && (a[idx] < v);
        int  c     = __popcll(__ballot(lt));
        int  nlo   = lo + c * stride;
        int  nhi   = nlo + stride;
        if (nhi > hi) nhi = hi;
        lo = nlo; hi = nhi;
    }
    int idx = lo + lane;
    bool ge = (idx >= hi) || (a[idx] >= v);
    unsigned long long bal = __ballot(ge);
    return bal ? (lo + __ffsll(bal) - 1) : hi;
}

// Per-element compute on one vec4-triple (ext_vector: indexed access).
#define PROC(p, t, m)                                                          \
    do {                                                                       \
        float m0 = (float)(m)[0], m1 = (float)(m)[1],                          \
              m2 = (float)(m)[2], m3 = (float)(m)[3];                          \
        accb += bce_elem((p)[0] * m0, (t)[0]);  accc += m0;                    \
        accb += bce_elem((p)[1] * m1, (t)[1]);  accc += m1;                    \
        accb += bce_elem((p)[2] * m2, (t)[2]);  accc += m2;                    \
        accb += bce_elem((p)[3] * m3, (t)[3]);  accc += m3;                    \
    } while (0)

// One block per segment (B=2048 -> 8 blocks/CU, all co-resident).
// Round-3 lesson: NO agent-scope fences / fused final sum -- per-block
// __threadfence on 8-XCD CDNA4 triggers L2 writeback storms (43 -> 212 us).
// Round-5 experiment (r4 intent, type-fixed): non-temporal stream loads.
// The harness's 268 MB fill leaves L2/L3 dirty; normal read-allocates evict
// those lines -> ~65 MB of writeback rides on our reads (r0-r2: FETCH 65 +
// WRITE 65 MB = 3.0 TB/s). nt loads skip allocation: writebacks leave our
// critical path; the fill kernel proves ~6.6 TB/s pure-stream is available.
__global__ __launch_bounds__(BLOCK, 8) void seg_kernel(
    const float* __restrict__ pred, const float* __restrict__ tgt,
    const int* __restrict__ batch, const int* __restrict__ mask,
    const float* __restrict__ sat_pred, const float* __restrict__ sat_tgt,
    float* __restrict__ per_graph, int n, int Bseg)
{
    const int b   = blockIdx.x;
    const int tid = threadIdx.x;

    __shared__ int sh_bounds[2];
    const int wid = tid >> 6;
    if (wid < 2) {                            // wave 0 -> lo, wave 1 -> hi, concurrent
        int r = wave_lower_bound(batch, n, b + wid);
        if ((tid & 63) == 0) sh_bounds[wid] = r;
    }
    __syncthreads();
    const int lo = sh_bounds[0], hi = sh_bounds[1];   // block owns batch range [lo,hi)

    float accb = 0.0f, accc = 0.0f;

    int a0 = (lo + 3) & ~3;                   // first 16B-aligned element
    if (a0 > hi) a0 = hi;
    const int nvec = (hi - a0) >> 2;
    const int a1   = a0 + (nvec << 2);

    // scalar head (<=3 elems)
    for (int i = lo + tid; i < a0; i += BLOCK) {
        float mf = (float)mask[i];
        accb += bce_elem(pred[i] * mf, tgt[i]);
        accc += mf;
    }

    // vector body: 3 coalesced 16B streams, 3x unroll, ALL loads non-temporal.
    const fx4* p4 = reinterpret_cast<const fx4*>(pred) + (a0 >> 2);
    const fx4* t4 = reinterpret_cast<const fx4*>(tgt)  + (a0 >> 2);
    const ix4* m4 = reinterpret_cast<const ix4*>(mask) + (a0 >> 2);

    int i = tid;
    const int nv2 = nvec - 2 * BLOCK;
    for (; i < nv2; i += 3 * BLOCK) {
        fx4 pa = __builtin_nontemporal_load(p4 + i);
        fx4 pb = __builtin_nontemporal_load(p4 + i + BLOCK);
        fx4 pc = __builtin_nontemporal_load(p4 + i + 2 * BLOCK);
        fx4 ta = __builtin_nontemporal_load(t4 + i);
        fx4 tb = __builtin_nontemporal_load(t4 + i + BLOCK);
        fx4 tc = __builtin_nontemporal_load(t4 + i + 2 * BLOCK);
        ix4 ma = __builtin_nontemporal_load(m4 + i);
        ix4 mb = __builtin_nontemporal_load(m4 + i + BLOCK);
        ix4 mc = __builtin_nontemporal_load(m4 + i + 2 * BLOCK);
        PROC(pa, ta, ma);
        PROC(pb, tb, mb);
        PROC(pc, tc, mc);
    }
    for (; i < nvec; i += BLOCK) {            // remainder (<=2 strided iters/thread)
        fx4 p = __builtin_nontemporal_load(p4 + i);
        fx4 t = __builtin_nontemporal_load(t4 + i);
        ix4 m = __builtin_nontemporal_load(m4 + i);
        PROC(p, t, m);
    }

    // scalar tail (<=3 elems)
    for (int k = a1 + tid; k < hi; k += BLOCK) {
        float mf = (float)mask[k];
        accb += bce_elem(pred[k] * mf, tgt[k]);
        accc += mf;
    }

    // block reduction: wave shfl -> LDS -> thread 0
    #pragma unroll
    for (int o = 32; o > 0; o >>= 1) {
        accb += __shfl_xor(accb, o);
        accc += __shfl_xor(accc, o);
    }
    __shared__ float wb[4], wc[4];
    if ((tid & 63) == 0) { wb[tid >> 6] = accb; wc[tid >> 6] = accc; }
    __syncthreads();
    if (tid == 0) {
        float sb = wb[0] + wb[1] + wb[2] + wb[3];
        float sc = wc[0] + wc[1] + wc[2] + wc[3];
        float pg = (sc > 0.0f) ? sb / fmaxf(sc, 1.0f) : 0.0f;
        // fold this graph's share of the sat-BCE mean*L1 term; every b covered once
        pg += bce_elem(sat_pred[b], sat_tgt[b]) * ((1.0f / 50.0f) / (float)Bseg);
        per_graph[b] = pg;                    // plain store: no atomics, no fences
    }
}

__global__ __launch_bounds__(256) void sum_kernel(
    const float* __restrict__ per_graph, float* __restrict__ out, int Bseg)
{
    float local = 0.0f;
    for (int i = threadIdx.x; i < Bseg; i += 256) local += per_graph[i];
    #pragma unroll
    for (int o = 32; o > 0; o >>= 1) local += __shfl_xor(local, o);
    __shared__ float ws[4];
    if ((threadIdx.x & 63) == 0) ws[threadIdx.x >> 6] = local;
    __syncthreads();
    if (threadIdx.x == 0) out[0] = ws[0] + ws[1] + ws[2] + ws[3];
}

extern "C" void kernel_launch(void* const* d_in, const int* in_sizes, int n_in,
                              void* d_out, int out_size, void* d_ws, size_t ws_size,
                              hipStream_t stream) {
    const float* y_mus_pred = (const float*)d_in[0];
    const float* y_mus      = (const float*)d_in[1];
    const float* y_sat_pred = (const float*)d_in[2];
    const float* y_sat      = (const float*)d_in[3];
    const int*   batch      = (const int*)d_in[4];
    const int*   mask       = (const int*)d_in[5];

    const int n    = in_sizes[0];
    const int Bseg = in_sizes[2];

    float* per_graph = (float*)d_ws;   // Bseg floats; every slot written each launch

    seg_kernel<<<Bseg, BLOCK, 0, stream>>>(
        y_mus_pred, y_mus, batch, mask, y_sat_pred, y_sat, per_graph, n, Bseg);
    sum_kernel<<<1, 256, 0, stream>>>(per_graph, (float*)d_out, Bseg);
}